// Round 1
// baseline (639.534 us; speedup 1.0000x reference)
//
#include <hip/hip_runtime.h>

// 2:4 structured sparsity over channel groups of x:[64,512,56,56] fp32.
// Memory-bound streaming kernel: 411 MB in + 411 MB out.

namespace {
constexpr int kHW    = 56 * 56;        // 3136 (spatial, contiguous)
constexpr int kHW4   = kHW / 4;        // 784 float4s per channel-plane
constexpr int kC     = 512;
constexpr int kG     = kC / 4;         // 128 groups of 4 channels
constexpr int kN     = 64;
constexpr int kTotal = kN * kG * kHW4; // 6,422,528 threads; /256 = 25088 blocks exactly
}  // namespace

// Keep rule replicating jax top_k tie-break (drop 2 smallest |x|, lower index
// dropped first on ties): keep i iff #{j: a_j > a_i || (a_j==a_i && j>i)} < 2.
// For j>i the relation is (a_j >= a_i); for j<i it is (a_j > a_i).
__device__ __forceinline__ void mask_quad(float x0, float x1, float x2, float x3,
                                          float& o0, float& o1, float& o2, float& o3) {
    float a0 = fabsf(x0), a1 = fabsf(x1), a2 = fabsf(x2), a3 = fabsf(x3);
    int c0 = (a1 >= a0) + (a2 >= a0) + (a3 >= a0);
    int c1 = (a0 >  a1) + (a2 >= a1) + (a3 >= a1);
    int c2 = (a0 >  a2) + (a1 >  a2) + (a3 >= a2);
    int c3 = (a0 >  a3) + (a1 >  a3) + (a2 >  a3);
    o0 = (c0 < 2) ? x0 : 0.0f;
    o1 = (c1 < 2) ? x1 : 0.0f;
    o2 = (c2 < 2) ? x2 : 0.0f;
    o3 = (c3 < 2) ? x3 : 0.0f;
}

__global__ __launch_bounds__(256) void sp24_kernel(const float* __restrict__ x,
                                                   float* __restrict__ out) {
    int t = blockIdx.x * 256 + threadIdx.x;
    // t -> (n, g, hw4): spatial-fastest so consecutive lanes read consecutive float4s.
    int hw4  = t % kHW4;
    int rest = t / kHW4;
    int g    = rest % kG;
    int n    = rest / kG;

    size_t base = (size_t)(n * kC + g * 4) * kHW + (size_t)hw4 * 4;

    float4 v0 = *reinterpret_cast<const float4*>(x + base);
    float4 v1 = *reinterpret_cast<const float4*>(x + base + kHW);
    float4 v2 = *reinterpret_cast<const float4*>(x + base + 2 * (size_t)kHW);
    float4 v3 = *reinterpret_cast<const float4*>(x + base + 3 * (size_t)kHW);

    float4 o0, o1, o2, o3;
    mask_quad(v0.x, v1.x, v2.x, v3.x, o0.x, o1.x, o2.x, o3.x);
    mask_quad(v0.y, v1.y, v2.y, v3.y, o0.y, o1.y, o2.y, o3.y);
    mask_quad(v0.z, v1.z, v2.z, v3.z, o0.z, o1.z, o2.z, o3.z);
    mask_quad(v0.w, v1.w, v2.w, v3.w, o0.w, o1.w, o2.w, o3.w);

    *reinterpret_cast<float4*>(out + base)                    = o0;
    *reinterpret_cast<float4*>(out + base + kHW)              = o1;
    *reinterpret_cast<float4*>(out + base + 2 * (size_t)kHW)  = o2;
    *reinterpret_cast<float4*>(out + base + 3 * (size_t)kHW)  = o3;
}

extern "C" void kernel_launch(void* const* d_in, const int* in_sizes, int n_in,
                              void* d_out, int out_size, void* d_ws, size_t ws_size,
                              hipStream_t stream) {
    const float* x = (const float*)d_in[0];
    float* out = (float*)d_out;
    sp24_kernel<<<kTotal / 256, 256, 0, stream>>>(x, out);
}